// Round 5
// baseline (194.133 us; speedup 1.0000x reference)
//
#include <hip/hip_runtime.h>
#include <hip/hip_bf16.h>

#define NT 10      // spline knots
#define NC 256     // channels
#define EPS 1e-5f
#define HW4 784    // (56*56)/4 float4s per (b,c) plane
#define TPB 256
#define ILP 4      // float4s per thread

// ---------------------------------------------------------------------------
// Kernel 1: one thread per channel. Natural cubic spline via Thomas algorithm.
// Fully unrolled, statically indexed, cndmask-chain interval select. ~3 us.
// ---------------------------------------------------------------------------
__device__ __forceinline__ float spline_eval_channel(
        const float* __restrict__ param,   // [NT, NC]
        const float* __restrict__ times,   // LDS, [NT]
        float t, int c) {
    float y[NT];
#pragma unroll
    for (int i = 0; i < NT; ++i) y[i] = param[i * NC + c];

    float h[NT - 1], slopes[NT - 1];
#pragma unroll
    for (int i = 0; i < NT - 1; ++i) {
        h[i] = times[i + 1] - times[i];
        slopes[i] = (y[i + 1] - y[i]) / h[i];
    }

    float rhs[NT - 2], diag[NT - 2], sup[NT - 3];
#pragma unroll
    for (int i = 0; i < NT - 2; ++i) {
        rhs[i]  = 6.0f * (slopes[i + 1] - slopes[i]);
        diag[i] = 2.0f * (h[i] + h[i + 1]);
    }
#pragma unroll
    for (int i = 0; i < NT - 3; ++i) sup[i] = h[i + 1];

#pragma unroll
    for (int i = 1; i < NT - 2; ++i) {
        float w = sup[i - 1] / diag[i - 1];
        diag[i] -= w * sup[i - 1];
        rhs[i]  -= w * rhs[i - 1];
    }
    float m[NT];
    m[0] = 0.0f;
    m[NT - 1] = 0.0f;
    m[NT - 2] = rhs[NT - 3] / diag[NT - 3];
#pragma unroll
    for (int i = NT - 4; i >= 0; --i)
        m[i + 1] = (rhs[i] - sup[i] * m[i + 2]) / diag[i];

    float bco[NT - 1], cco[NT - 1], dco[NT - 1];
#pragma unroll
    for (int i = 0; i < NT - 1; ++i) {
        bco[i] = slopes[i] - h[i] * (2.0f * m[i] + m[i + 1]) * (1.0f / 6.0f);
        cco[i] = m[i] * 0.5f;
        dco[i] = (m[i + 1] - m[i]) / (6.0f * h[i]);
    }

    float A = y[0], Bf = bco[0], Cf = cco[0], Df = dco[0], u = t - times[0];
#pragma unroll
    for (int i = 1; i <= NT - 2; ++i) {
        bool sel = (times[i] <= t);
        if (sel) { A = y[i]; Bf = bco[i]; Cf = cco[i]; Df = dco[i]; u = t - times[i]; }
    }
    return A + u * (Bf + u * (Cf + u * Df));
}

__global__ void spline_coeffs_kernel(const float* __restrict__ means,
                                     const float* __restrict__ vars_,
                                     const float* __restrict__ bnw,
                                     const float* __restrict__ bnb,
                                     const float* __restrict__ times_g,
                                     const float* __restrict__ t_g,
                                     float* __restrict__ ws) {
    __shared__ float times[NT];
    if (threadIdx.x < NT) times[threadIdx.x] = times_g[threadIdx.x];
    __syncthreads();
    const float t = t_g[0];
    const int c = threadIdx.x;  // 256 threads == 256 channels

    float mean   = spline_eval_channel(means, times, t, c);
    float var    = spline_eval_channel(vars_, times, t, c);
    float weight = spline_eval_channel(bnw,   times, t, c);
    float bias   = spline_eval_channel(bnb,   times, t, c);

    float inv = 1.0f / sqrtf(var + EPS);
    float s   = weight * inv;
    ws[c]      = s;               // scale
    ws[NC + c] = bias - mean * s; // shift
}

// ---------------------------------------------------------------------------
// Kernel 2: 4 independent float4s per thread (ILP=4), coalesced via
// intra-block stride-TPB. Block covers TPB*ILP=1024 consecutive float4s.
// n4 = 6,422,528 = 6272 * 1024 exactly -> no tail.
// ---------------------------------------------------------------------------
__global__ void apply_kernel(const float4* __restrict__ x,
                             const float* __restrict__ ws,
                             float4* __restrict__ out, int n4) {
    int base = blockIdx.x * (TPB * ILP) + threadIdx.x;

    // 4 independent loads in flight
    float4 v0 = x[base];
    float4 v1 = x[base + TPB];
    float4 v2 = x[base + 2 * TPB];
    float4 v3 = x[base + 3 * TPB];

    int c0 = ((base)           / HW4) & (NC - 1);
    int c1 = ((base + TPB)     / HW4) & (NC - 1);
    int c2 = ((base + 2 * TPB) / HW4) & (NC - 1);
    int c3 = ((base + 3 * TPB) / HW4) & (NC - 1);

    float s0 = ws[c0], sh0 = ws[NC + c0];
    float s1 = ws[c1], sh1 = ws[NC + c1];
    float s2 = ws[c2], sh2 = ws[NC + c2];
    float s3 = ws[c3], sh3 = ws[NC + c3];

    v0.x = fmaf(v0.x, s0, sh0); v0.y = fmaf(v0.y, s0, sh0);
    v0.z = fmaf(v0.z, s0, sh0); v0.w = fmaf(v0.w, s0, sh0);
    v1.x = fmaf(v1.x, s1, sh1); v1.y = fmaf(v1.y, s1, sh1);
    v1.z = fmaf(v1.z, s1, sh1); v1.w = fmaf(v1.w, s1, sh1);
    v2.x = fmaf(v2.x, s2, sh2); v2.y = fmaf(v2.y, s2, sh2);
    v2.z = fmaf(v2.z, s2, sh2); v2.w = fmaf(v2.w, s2, sh2);
    v3.x = fmaf(v3.x, s3, sh3); v3.y = fmaf(v3.y, s3, sh3);
    v3.z = fmaf(v3.z, s3, sh3); v3.w = fmaf(v3.w, s3, sh3);

    out[base]           = v0;
    out[base + TPB]     = v1;
    out[base + 2 * TPB] = v2;
    out[base + 3 * TPB] = v3;
}

extern "C" void kernel_launch(void* const* d_in, const int* in_sizes, int n_in,
                              void* d_out, int out_size, void* d_ws, size_t ws_size,
                              hipStream_t stream) {
    const float* x     = (const float*)d_in[0];
    const float* means = (const float*)d_in[1];
    const float* vars_ = (const float*)d_in[2];
    const float* bnw   = (const float*)d_in[3];
    const float* bnb   = (const float*)d_in[4];
    const float* times = (const float*)d_in[5];
    const float* t     = (const float*)d_in[6];
    float* out = (float*)d_out;
    float* ws  = (float*)d_ws;   // [2*NC] floats: scale then shift

    spline_coeffs_kernel<<<1, NC, 0, stream>>>(means, vars_, bnw, bnb, times, t, ws);

    int n4 = out_size / 4;                   // 6,422,528
    int blocks = n4 / (TPB * ILP);           // 6272, exact
    apply_kernel<<<blocks, TPB, 0, stream>>>((const float4*)x, ws, (float4*)out, n4);
}